// Round 5
// baseline (72732.532 us; speedup 1.0000x reference)
//
#include <hip/hip_runtime.h>
#include <stdint.h>

// ---------------------------------------------------------------------------
// StateTrackingRecurrentCell: B=8, S=2048, H=1024
// Barrier-free persistent scan with epoch-tagged dataflow words.
// R5: exchange words use SYSTEM-scope atomics (sc0+sc1 -> bypass L1+L2,
// write-through/read-through the coherence point). R2/R4 showed agent-scope
// relaxed stores linger in the producer XCD's private L2 (visibility gated
// by eviction, ~30us/step); system scope makes publish/poll event-driven.
//   state f32 -> one 64-bit word: [tag|hi16][tag|lo16]
//   rn   bf16 -> one 32-bit word: [tag|bf16]
// Double-buffered by step parity; dependency chain bounds skew < 2 steps.
// ---------------------------------------------------------------------------

#define Hd   1024
#define Bb   8
#define Ss   2048
#define BSr  (Bb * Ss)      // 16384 rows
#define NWG  64             // scan workgroups (<=256 CUs -> co-resident)
#define COLS 16             // output columns owned per scan WG
#define EPSf 1e-5f

typedef __attribute__((ext_vector_type(8))) short bf16x8;
typedef __attribute__((ext_vector_type(4))) float f32x4;

// workspace layout (bytes)
#define OFF_STW   0u                                   // u64 [2][8][1024] = 128KB
#define OFF_RNW   131072u                              // u32 [2][8][1024] = 64KB
#define OFF_NH    196608u                              // bf16 [16384][1024] = 32MB
#define OFF_WCAT  (OFF_NH + (size_t)BSr * Hd * 2)      // bf16 [3072][1024]  = 6MB
#define OFF_XCAT  (OFF_WCAT + (size_t)3072 * Hd * 2)   // bf16 x-projections = 96MB

#define SCAN_LDS 131712      // 3x32KB weights + 32KB A-frags + st_own + mv

#define SCOPE_X __HIP_MEMORY_SCOPE_SYSTEM   // exchange-word scope (the R5 change)

__device__ __forceinline__ unsigned f2bf(float f) {
  unsigned u = __float_as_uint(f);
  return (u + 0x7FFFu + ((u >> 16) & 1u)) >> 16;   // RNE f32->bf16
}
__device__ __forceinline__ float bf2f(unsigned short s) {
  return __uint_as_float(((unsigned)s) << 16);
}

// ---------------------------------------------------------------------------
// Kernel 1: input LN -> nh(bf16);  x-half weight convert -> Wcat(bf16);
//           tagged initial state (tag=0).
// ---------------------------------------------------------------------------
__global__ __launch_bounds__(256) void k_prep(
    const float* __restrict__ hidden, const float* __restrict__ in_g,
    const float* __restrict__ in_b, const float* __restrict__ prev_state,
    const float* __restrict__ Wu, const float* __restrict__ Wr,
    const float* __restrict__ Wo,
    unsigned short* __restrict__ nh, unsigned short* __restrict__ Wcat,
    unsigned long long* __restrict__ stw)
{
  __shared__ float rs[4], rq[4], mvv[2];
  const int bx = blockIdx.x, tid = threadIdx.x;
  if (bx < BSr) {
    // one block per row: LayerNorm(hidden[row]) * in_g + in_b -> bf16
    float4 v = *(const float4*)(hidden + (size_t)bx * Hd + tid * 4);
    float s = v.x + v.y + v.z + v.w;
    float q = v.x * v.x + v.y * v.y + v.z * v.z + v.w * v.w;
#pragma unroll
    for (int m = 1; m < 64; m <<= 1) { s += __shfl_xor(s, m); q += __shfl_xor(q, m); }
    if ((tid & 63) == 0) { rs[tid >> 6] = s; rq[tid >> 6] = q; }
    __syncthreads();
    if (tid == 0) {
      float ts = rs[0] + rs[1] + rs[2] + rs[3];
      float tq = rq[0] + rq[1] + rq[2] + rq[3];
      float m = ts * (1.0f / Hd);
      mvv[0] = m;
      mvv[1] = rsqrtf(tq * (1.0f / Hd) - m * m + EPSf);
    }
    __syncthreads();
    float m = mvv[0], rstd = mvv[1];
    float4 g  = *(const float4*)(in_g + tid * 4);
    float4 b4 = *(const float4*)(in_b + tid * 4);
    unsigned r0 = f2bf((v.x - m) * rstd * g.x + b4.x);
    unsigned r1 = f2bf((v.y - m) * rstd * g.y + b4.y);
    unsigned r2 = f2bf((v.z - m) * rstd * g.z + b4.z);
    unsigned r3 = f2bf((v.w - m) * rstd * g.w + b4.w);
    uint2 pk; pk.x = r0 | (r1 << 16); pk.y = r2 | (r3 << 16);
    *(uint2*)(nh + (size_t)bx * Hd + tid * 4) = pk;
  } else if (bx < BSr + 3072) {
    // Wcat[q][k] = bf16(W_mat[i][k]) for k in [0,1024)  (x-side halves)
    const int q2 = bx - BSr;
    const float* W = (q2 < 1024) ? Wu : (q2 < 2048) ? Wr : Wo;
    const int i = q2 & 1023;
    float4 v = *(const float4*)(W + (size_t)i * 2048 + tid * 4);
    unsigned r0 = f2bf(v.x), r1 = f2bf(v.y), r2 = f2bf(v.z), r3 = f2bf(v.w);
    uint2 pk; pk.x = r0 | (r1 << 16); pk.y = r2 | (r3 << 16);
    *(uint2*)(Wcat + (size_t)q2 * Hd + tid * 4) = pk;
  } else {
    // tagged initial state, tag = 0, parity buffer 0
    for (int j = tid; j < Bb * Hd; j += 256) {
      unsigned bits = __float_as_uint(prev_state[j]);
      unsigned hi = bits >> 16;           // (0<<16)|hi
      unsigned lo = bits & 0xFFFFu;       // (0<<16)|lo
      __hip_atomic_store(stw + j, ((unsigned long long)hi << 32) | lo,
                         __ATOMIC_RELAXED, SCOPE_X);
    }
  }
}

// ---------------------------------------------------------------------------
// Kernel 2: xcat = nh @ Wcat^T + bias  (M=16384, N=3072, K=1024, bf16 MFMA)
// Output layout optimized for scan reads:
//   idx = ((t*64 + col/16)*3 + mat)*128 + b*16 + (col&15)   (bf16)
// ---------------------------------------------------------------------------
__global__ __launch_bounds__(256) void k_gemm(
    const unsigned short* __restrict__ nh, const unsigned short* __restrict__ Wcat,
    const float* __restrict__ bu, const float* __restrict__ br,
    const float* __restrict__ bo, unsigned short* __restrict__ xcat)
{
  __shared__ unsigned short aA[8 * 64 * 8];   // A-frags, linear per (rowtile,lane)
  __shared__ unsigned short aB[8 * 64 * 8];
  const int tid = threadIdx.x, bx = blockIdx.x;
  const int mt = bx & 127, nt = bx >> 7;      // 128 x 24 tiles of 128x128
  const int mb = mt * 128, nb = nt * 128;
  const int lane = tid & 63, wave = tid >> 6;
  const int wm = wave >> 1, wn = wave & 1;

  f32x4 acc[4][4];
  f32x4 zz = {0.f, 0.f, 0.f, 0.f};
#pragma unroll
  for (int mi = 0; mi < 4; ++mi)
#pragma unroll
    for (int ni = 0; ni < 4; ++ni) acc[mi][ni] = zz;

  for (int ks = 0; ks < 32; ++ks) {
    const int k0 = ks * 32;
#pragma unroll
    for (int it = 0; it < 4; ++it) {
      int gidx = tid + it * 256;
      int slot = gidx >> 6, l = gidx & 63;
      int kk = k0 + ((l >> 4) << 3);
      int r16 = slot & 7;
      if (slot < 8) {
        int row = mb + r16 * 16 + (l & 15);
        uint4 v = *(const uint4*)(nh + (size_t)row * Hd + kk);
        *(uint4*)(aA + (size_t)(r16 * 64 + l) * 8) = v;
      } else {
        int row = nb + r16 * 16 + (l & 15);
        uint4 v = *(const uint4*)(Wcat + (size_t)row * Hd + kk);
        *(uint4*)(aB + (size_t)(r16 * 64 + l) * 8) = v;
      }
    }
    __syncthreads();
    bf16x8 af_[4], bf_[4];
#pragma unroll
    for (int mi = 0; mi < 4; ++mi)
      af_[mi] = *(const bf16x8*)(aA + ((wm * 4 + mi) * 64 + lane) * 8);
#pragma unroll
    for (int ni = 0; ni < 4; ++ni)
      bf_[ni] = *(const bf16x8*)(aB + ((wn * 4 + ni) * 64 + lane) * 8);
#pragma unroll
    for (int mi = 0; mi < 4; ++mi)
#pragma unroll
      for (int ni = 0; ni < 4; ++ni)
        acc[mi][ni] = __builtin_amdgcn_mfma_f32_16x16x32_bf16(af_[mi], bf_[ni], acc[mi][ni], 0, 0, 0);
    __syncthreads();
  }

#pragma unroll
  for (int ni = 0; ni < 4; ++ni) {
    int n = nb + wn * 64 + ni * 16 + (lane & 15);
    int mat = n >> 10, col = n & 1023;
    float bias = (mat == 0) ? bu[col] : (mat == 1) ? br[col] : bo[col];
#pragma unroll
    for (int mi = 0; mi < 4; ++mi) {
#pragma unroll
      for (int ii = 0; ii < 4; ++ii) {
        int mrow = mb + wm * 64 + mi * 16 + ((lane >> 4) << 2) + ii;
        int b = mrow >> 11, t = mrow & 2047;
        size_t idx = ((size_t)(t * 64 + (col >> 4)) * 3 + mat) * 128 + b * 16 + (col & 15);
        xcat[idx] = (unsigned short)f2bf(acc[mi][ni][ii] + bias);
      }
    }
  }
}

// ---------------------------------------------------------------------------
// Kernel 3: barrier-free persistent scan. 64 WGs x 256 threads. Each WG owns
// 16 output columns; state-side weights resident in LDS in B-frag order.
// ---------------------------------------------------------------------------
__global__ __launch_bounds__(256, 1) void k_scan(
    const float* __restrict__ Wu, const float* __restrict__ Wr,
    const float* __restrict__ Wo,
    const float* __restrict__ st_g, const float* __restrict__ st_b,
    const float* __restrict__ out_g, const float* __restrict__ out_b,
    const unsigned short* __restrict__ xcat,
    const float* __restrict__ prev_state,
    unsigned long long* __restrict__ stw, unsigned* __restrict__ rnw,
    float* __restrict__ out)
{
  extern __shared__ char smem[];
  unsigned short* wU = (unsigned short*)smem;          // [2048*8] bf16 = 32KB
  unsigned short* wR = wU + 2048 * 8;
  unsigned short* wO = wR + 2048 * 8;
  char*  afb    = (char*)(wO + 2048 * 8);              // 32KB A-frag buffer
  float* st_own = (float*)(afb + 32768);               // [128] state at owned cols
  float* mv     = st_own + 128;                        // [16] per-batch sum/sumsq

  const int tid = threadIdx.x;
  const int wg = blockIdx.x;
  const int colbase = wg * COLS;
  const int lane = tid & 63;
  const int wave = tid >> 6;
  const int bmy = tid >> 5;      // batch row this thread handles (0..7)
  const int imy = tid & 31;      // k-chunk (32 elems) within the row
  const int k0my = imy * 32;

  // ---- one-time init: weight fragments into LDS (B-frag order, linear) ----
  for (int mtx = 0; mtx < 3; ++mtx) {
    const float* W = (mtx == 0) ? Wu : (mtx == 1) ? Wr : Wo;
    unsigned short* dst = (mtx == 0) ? wU : (mtx == 1) ? wR : wO;
    for (int s = tid; s < 2048; s += 256) {
      int ks = s >> 6, l = s & 63;
      int c = l & 15, kg = l >> 4;
      int k0 = ks * 32 + kg * 8;
      const float* src = W + (size_t)(colbase + c) * 2048 + 1024 + k0;
      float4 v0 = *(const float4*)(src);
      float4 v1 = *(const float4*)(src + 4);
      bf16x8 pk;
      pk[0] = (short)f2bf(v0.x); pk[1] = (short)f2bf(v0.y);
      pk[2] = (short)f2bf(v0.z); pk[3] = (short)f2bf(v0.w);
      pk[4] = (short)f2bf(v1.x); pk[5] = (short)f2bf(v1.y);
      pk[6] = (short)f2bf(v1.z); pk[7] = (short)f2bf(v1.w);
      *(bf16x8*)(dst + (size_t)s * 8) = pk;
    }
  }
  // zero A-frag rows 8..15 (padding batch rows) once; never rewritten
  for (int s = tid; s < 2048; s += 256) {
    int l = s & 63, ks = s >> 6;
    if ((l & 15) >= 8)
      *(uint4*)(afb + (((s * 16) ^ ((ks & 7) << 4)))) = make_uint4(0, 0, 0, 0);
  }
  // per-thread constants: st gamma/beta over this thread's fixed k-slice
  float stg[32], stb[32];
#pragma unroll
  for (int j = 0; j < 32; j += 4) {
    float4 g = *(const float4*)(st_g + k0my + j);
    stg[j] = g.x; stg[j + 1] = g.y; stg[j + 2] = g.z; stg[j + 3] = g.w;
    float4 b4 = *(const float4*)(st_b + k0my + j);
    stb[j] = b4.x; stb[j + 1] = b4.y; stb[j + 2] = b4.z; stb[j + 3] = b4.w;
  }
  float outg_my = 0.f, outb_my = 0.f, stgo = 0.f, stbo = 0.f;
  if (tid < 128) {
    int c = colbase + (tid & 15);
    outg_my = out_g[c]; outb_my = out_b[c];
    st_own[tid] = prev_state[(tid >> 4) * Hd + c];
  }
  if (wave == 1 && lane < 32) {
    int c = colbase + (lane & 15);
    stgo = st_g[c]; stbo = st_b[c];
  }
  __syncthreads();

  float uv[4] = {0.f, 0.f, 0.f, 0.f};

  for (int t = 0; t < Ss; ++t) {
    // prefetch x-projections for this step (independent of state)
    float xu[4] = {0, 0, 0, 0}, xo[4] = {0, 0, 0, 0}, xr[4] = {0, 0, 0, 0};
    if (lane < 32) {
      int b4i = (lane >> 4) * 4, c = lane & 15;
      size_t base = ((size_t)(t * 64 + wg) * 3) * 128;
      if (wave == 0) {
#pragma unroll
        for (int i = 0; i < 4; ++i) {
          xu[i] = bf2f(xcat[base + 0 * 128 + (b4i + i) * 16 + c]);
          xo[i] = bf2f(xcat[base + 2 * 128 + (b4i + i) * 16 + c]);
        }
      } else if (wave == 1) {
#pragma unroll
        for (int i = 0; i < 4; ++i)
          xr[i] = bf2f(xcat[base + 1 * 128 + (b4i + i) * 16 + c]);
      }
    }

    // ---- phase A: batched poll of tagged state (tag = t, parity = t&1) ----
    const unsigned long long* sp = stw + (size_t)(t & 1) * 8192 + bmy * 1024 + k0my;
    const unsigned tgA = (unsigned)t;
    unsigned long long w64[32];
    for (;;) {
#pragma unroll
      for (int j = 0; j < 32; ++j)
        w64[j] = __hip_atomic_load(sp + j, __ATOMIC_RELAXED, SCOPE_X);
      unsigned bad = 0;
#pragma unroll
      for (int j = 0; j < 32; ++j)
        bad |= ((unsigned)(w64[j] >> 48) ^ tgA) |
               (((unsigned)(w64[j] >> 16) & 0xFFFFu) ^ tgA);
      if (bad == 0) break;
    }
    float sv[32];
#pragma unroll
    for (int j = 0; j < 32; ++j)
      sv[j] = __uint_as_float(((unsigned)(w64[j] >> 32) << 16) |
                              ((unsigned)w64[j] & 0xFFFFu));

    // per-batch mean/var
    float s = 0.f, q = 0.f;
#pragma unroll
    for (int j = 0; j < 32; ++j) { s += sv[j]; q += sv[j] * sv[j]; }
#pragma unroll
    for (int m = 1; m < 32; m <<= 1) { s += __shfl_xor(s, m); q += __shfl_xor(q, m); }
    if (imy == 0) { mv[bmy * 2] = s; mv[bmy * 2 + 1] = q; }
    __syncthreads();   // mv ready; also orders prev-step afb reads before rewrite

    // output write for step t-1 (LN_out of state_t at owned cols)
    if (tid < 128 && t > 0) {
      int b = tid >> 4, c = tid & 15;
      float sval = st_own[tid];
      float m = mv[b * 2] * (1.0f / Hd);
      float rstd = rsqrtf(mv[b * 2 + 1] * (1.0f / Hd) - m * m + EPSf);
      out[(size_t)b * Ss * Hd + (size_t)(t - 1) * Hd + colbase + c] =
          (sval - m) * rstd * outg_my + outb_my;
    }

    // build ns A-fragments (bf16, XOR-swizzled LDS)
    {
      float m = mv[bmy * 2] * (1.0f / Hd);
      float rstd = rsqrtf(mv[bmy * 2 + 1] * (1.0f / Hd) - m * m + EPSf);
#pragma unroll
      for (int kg = 0; kg < 4; ++kg) {
        bf16x8 pk;
#pragma unroll
        for (int j = 0; j < 8; ++j) {
          float f = (sv[kg * 8 + j] - m) * rstd * stg[kg * 8 + j] + stb[kg * 8 + j];
          pk[j] = (short)f2bf(f);
        }
        int sidx = imy * 64 + kg * 16 + bmy;
        *(bf16x8*)(afb + ((sidx * 16) ^ ((imy & 7) << 4))) = pk;
      }
    }
    __syncthreads();

    // MFMA: wave0 -> u, wave1 -> r (+ tagged rn store)
    if (wave < 2) {
      const unsigned short* wsel = (wave == 0) ? wU : wR;
      f32x4 acc = {0.f, 0.f, 0.f, 0.f};
#pragma unroll 4
      for (int ks = 0; ks < 32; ++ks) {
        bf16x8 a = *(const bf16x8*)(afb + (((ks * 64 + lane) * 16) ^ ((ks & 7) << 4)));
        bf16x8 w8 = *(const bf16x8*)(wsel + (size_t)(ks * 64 + lane) * 8);
        acc = __builtin_amdgcn_mfma_f32_16x16x32_bf16(a, w8, acc, 0, 0, 0);
      }
      if (lane < 32) {
        int c = lane & 15;
#pragma unroll
        for (int i = 0; i < 4; ++i) {
          int b = (lane >> 4) * 4 + i;
          if (wave == 0) {
            float pre = acc[i] + xu[i];
            uv[i] = 1.0f / (1.0f + __expf(-pre));
          } else {
            float pre = acc[i] + xr[i];
            float rvv = 1.0f / (1.0f + __expf(-pre));
            float m = mv[b * 2] * (1.0f / Hd);
            float rstd = rsqrtf(mv[b * 2 + 1] * (1.0f / Hd) - m * m + EPSf);
            float nso = (st_own[b * 16 + c] - m) * rstd * stgo + stbo;
            float rn = rvv * nso;
            __hip_atomic_store(rnw + (size_t)(t & 1) * 8192 + b * 1024 + colbase + c,
                               (((unsigned)(t + 1)) << 16) | f2bf(rn),
                               __ATOMIC_RELAXED, SCOPE_X);
          }
        }
      }
    }

    // ---- phase B: batched poll of tagged rn (tag = t+1, parity = t&1) ----
    const unsigned* rp = rnw + (size_t)(t & 1) * 8192 + bmy * 1024 + k0my;
    const unsigned tgB = (unsigned)(t + 1);
    unsigned rw[32];
    for (;;) {
#pragma unroll
      for (int j = 0; j < 32; ++j)
        rw[j] = __hip_atomic_load(rp + j, __ATOMIC_RELAXED, SCOPE_X);
      unsigned bad = 0;
#pragma unroll
      for (int j = 0; j < 32; ++j) bad |= (rw[j] >> 16) ^ tgB;
      if (bad == 0) break;
    }

    __syncthreads();   // phase A MFMA afb reads complete before rewrite

    // build rn A-fragments
#pragma unroll
    for (int kg = 0; kg < 4; ++kg) {
      bf16x8 pk;
#pragma unroll
      for (int j = 0; j < 8; ++j)
        pk[j] = (short)(unsigned short)(rw[kg * 8 + j] & 0xFFFFu);
      int sidx = imy * 64 + kg * 16 + bmy;
      *(bf16x8*)(afb + ((sidx * 16) ^ ((imy & 7) << 4))) = pk;
    }
    __syncthreads();

    // candidate MFMA + state update (wave0), tagged state store
    if (wave == 0) {
      f32x4 acc = {0.f, 0.f, 0.f, 0.f};
#pragma unroll 4
      for (int ks = 0; ks < 32; ++ks) {
        bf16x8 a = *(const bf16x8*)(afb + (((ks * 64 + lane) * 16) ^ ((ks & 7) << 4)));
        bf16x8 w8 = *(const bf16x8*)(wO + (size_t)(ks * 64 + lane) * 8);
        acc = __builtin_amdgcn_mfma_f32_16x16x32_bf16(a, w8, acc, 0, 0, 0);
      }
      if (lane < 32) {
        int c = lane & 15;
        const unsigned tgS = (unsigned)(t + 1);
#pragma unroll
        for (int i = 0; i < 4; ++i) {
          int b = (lane >> 4) * 4 + i;
          float pre = acc[i] + xo[i];
          float cd = tanhf(pre);
          float sold = st_own[b * 16 + c];
          float nsv = (1.0f - uv[i]) * sold + uv[i] * cd;
          st_own[b * 16 + c] = nsv;
          unsigned bits = __float_as_uint(nsv);
          unsigned hi = (tgS << 16) | (bits >> 16);
          unsigned lo = (tgS << 16) | (bits & 0xFFFFu);
          __hip_atomic_store(stw + (size_t)((t + 1) & 1) * 8192 + b * 1024 + colbase + c,
                             ((unsigned long long)hi << 32) | lo,
                             __ATOMIC_RELAXED, SCOPE_X);
        }
      }
    }
    // no barrier — next step's polls provide the ordering
  }

  // ---- epilogue: out[S-1] + final_state (poll state tag Ss, parity 0) ----
  {
    const unsigned long long* sp = stw + (size_t)(Ss & 1) * 8192 + bmy * 1024 + k0my;
    const unsigned tg = (unsigned)Ss;
    unsigned long long w64[32];
    for (;;) {
#pragma unroll
      for (int j = 0; j < 32; ++j)
        w64[j] = __hip_atomic_load(sp + j, __ATOMIC_RELAXED, SCOPE_X);
      unsigned bad = 0;
#pragma unroll
      for (int j = 0; j < 32; ++j)
        bad |= ((unsigned)(w64[j] >> 48) ^ tg) |
               (((unsigned)(w64[j] >> 16) & 0xFFFFu) ^ tg);
      if (bad == 0) break;
    }
    float s = 0.f, q = 0.f;
#pragma unroll
    for (int j = 0; j < 32; ++j) {
      float f = __uint_as_float(((unsigned)(w64[j] >> 32) << 16) |
                                ((unsigned)w64[j] & 0xFFFFu));
      s += f; q += f * f;
    }
#pragma unroll
    for (int m = 1; m < 32; m <<= 1) { s += __shfl_xor(s, m); q += __shfl_xor(q, m); }
    if (imy == 0) { mv[bmy * 2] = s; mv[bmy * 2 + 1] = q; }
    __syncthreads();
    if (tid < 128) {
      int b = tid >> 4, c = tid & 15;
      float sval = st_own[tid];
      float m = mv[b * 2] * (1.0f / Hd);
      float rstd = rsqrtf(mv[b * 2 + 1] * (1.0f / Hd) - m * m + EPSf);
      out[(size_t)b * Ss * Hd + (size_t)(Ss - 1) * Hd + colbase + c] =
          (sval - m) * rstd * outg_my + outb_my;
      out[(size_t)Bb * Ss * Hd + b * Hd + colbase + c] = sval;
    }
  }
}

// ---------------------------------------------------------------------------
extern "C" void kernel_launch(void* const* d_in, const int* in_sizes, int n_in,
                              void* d_out, int out_size, void* d_ws, size_t ws_size,
                              hipStream_t stream) {
  const float* hidden = (const float*)d_in[0];
  const float* prev   = (const float*)d_in[1];
  const float* in_g   = (const float*)d_in[2];
  const float* in_b   = (const float*)d_in[3];
  const float* st_g   = (const float*)d_in[4];
  const float* st_b   = (const float*)d_in[5];
  const float* out_g  = (const float*)d_in[6];
  const float* out_b  = (const float*)d_in[7];
  const float* Wu     = (const float*)d_in[8];
  const float* bu     = (const float*)d_in[9];
  const float* Wr     = (const float*)d_in[10];
  const float* br     = (const float*)d_in[11];
  const float* Wo     = (const float*)d_in[12];
  const float* bo     = (const float*)d_in[13];

  char* ws = (char*)d_ws;
  unsigned long long* stw = (unsigned long long*)(ws + OFF_STW);
  unsigned*           rnw = (unsigned*)(ws + OFF_RNW);
  unsigned short*     nh   = (unsigned short*)(ws + OFF_NH);
  unsigned short*     Wcat = (unsigned short*)(ws + OFF_WCAT);
  unsigned short*     xcat = (unsigned short*)(ws + OFF_XCAT);
  float*              out  = (float*)d_out;

  (void)hipFuncSetAttribute(reinterpret_cast<const void*>(k_scan),
                            hipFuncAttributeMaxDynamicSharedMemorySize, SCAN_LDS);

  k_prep<<<dim3(BSr + 3072 + 1), dim3(256), 0, stream>>>(
      hidden, in_g, in_b, prev, Wu, Wr, Wo, nh, Wcat, stw);
  k_gemm<<<dim3(3072), dim3(256), 0, stream>>>(nh, Wcat, bu, br, bo, xcat);
  k_scan<<<dim3(NWG), dim3(256), SCAN_LDS, stream>>>(
      Wu, Wr, Wo, st_g, st_b, out_g, out_b, xcat, prev, stw, rnw, out);
}

// Round 7
// 24086.012 us; speedup vs baseline: 3.0197x; 3.0197x over previous
//
#include <hip/hip_runtime.h>
#include <stdint.h>

// ---------------------------------------------------------------------------
// StateTrackingRecurrentCell: B=8, S=2048, H=1024
// R7 = R6 (flag/payload-separated dataflow scan) + bugfix: out_g/out_b
// constants must be loaded by the waves that WRITE the output (waves 2/3).
// R6 loaded them only for tid<128 -> waves 2/3 wrote zeros (absmax 5.47).
//
// Protocol (unchanged): producers publish payload with system-scope
// write-through stores, s_waitcnt vmcnt(0), then set ONE padded per-WG flag.
// Consumers poll ONLY flags (wave0: 1 load/lane, ballot), then read payload
// exactly once. Monotonic flags + the dependency chain make single-buffer
// payloads safe (every producer's publish of step t+1 transitively waits on
// every consumer's read of step t).
// ---------------------------------------------------------------------------

#define Hd   1024
#define Bb   8
#define Ss   2048
#define BSr  (Bb * Ss)      // 16384 rows
#define NWG  64             // scan workgroups (<=256 CUs -> co-resident)
#define COLS 16             // output columns owned per scan WG
#define EPSf 1e-5f

typedef __attribute__((ext_vector_type(8))) short bf16x8;
typedef __attribute__((ext_vector_type(4))) float f32x4;

// workspace layout (bytes)
#define OFF_ST    0u                                   // f32 [8][1024] = 32KB
#define OFF_RN    32768u                               // u32 [8][1024] = 32KB
#define OFF_FLA   65536u                               // u32 [64][4] flags (16B pad)
#define OFF_FLB   66560u                               // u32 [64][4]
#define OFF_NH    196608u                              // bf16 [16384][1024] = 32MB
#define OFF_WCAT  (OFF_NH + (size_t)BSr * Hd * 2)      // bf16 [3072][1024]  = 6MB
#define OFF_XCAT  (OFF_WCAT + (size_t)3072 * Hd * 2)   // bf16 x-projections = 96MB

#define SCAN_LDS 131712      // 3x32KB weights + 32KB A-frags + st_own + mv

#define SC_SYS __HIP_MEMORY_SCOPE_SYSTEM

__device__ __forceinline__ unsigned f2bf(float f) {
  unsigned u = __float_as_uint(f);
  return (u + 0x7FFFu + ((u >> 16) & 1u)) >> 16;   // RNE f32->bf16
}
__device__ __forceinline__ float bf2f(unsigned short s) {
  return __uint_as_float(((unsigned)s) << 16);
}

// ---------------------------------------------------------------------------
// Kernel 1: input LN -> nh(bf16); x-half weight convert -> Wcat(bf16);
//           state init + flag zero.
// ---------------------------------------------------------------------------
__global__ __launch_bounds__(256) void k_prep(
    const float* __restrict__ hidden, const float* __restrict__ in_g,
    const float* __restrict__ in_b, const float* __restrict__ prev_state,
    const float* __restrict__ Wu, const float* __restrict__ Wr,
    const float* __restrict__ Wo,
    unsigned short* __restrict__ nh, unsigned short* __restrict__ Wcat,
    float* __restrict__ stf, unsigned* __restrict__ flA, unsigned* __restrict__ flB)
{
  __shared__ float rs[4], rq[4], mvv[2];
  const int bx = blockIdx.x, tid = threadIdx.x;
  if (bx < BSr) {
    float4 v = *(const float4*)(hidden + (size_t)bx * Hd + tid * 4);
    float s = v.x + v.y + v.z + v.w;
    float q = v.x * v.x + v.y * v.y + v.z * v.z + v.w * v.w;
#pragma unroll
    for (int m = 1; m < 64; m <<= 1) { s += __shfl_xor(s, m); q += __shfl_xor(q, m); }
    if ((tid & 63) == 0) { rs[tid >> 6] = s; rq[tid >> 6] = q; }
    __syncthreads();
    if (tid == 0) {
      float ts = rs[0] + rs[1] + rs[2] + rs[3];
      float tq = rq[0] + rq[1] + rq[2] + rq[3];
      float m = ts * (1.0f / Hd);
      mvv[0] = m;
      mvv[1] = rsqrtf(tq * (1.0f / Hd) - m * m + EPSf);
    }
    __syncthreads();
    float m = mvv[0], rstd = mvv[1];
    float4 g  = *(const float4*)(in_g + tid * 4);
    float4 b4 = *(const float4*)(in_b + tid * 4);
    unsigned r0 = f2bf((v.x - m) * rstd * g.x + b4.x);
    unsigned r1 = f2bf((v.y - m) * rstd * g.y + b4.y);
    unsigned r2 = f2bf((v.z - m) * rstd * g.z + b4.z);
    unsigned r3 = f2bf((v.w - m) * rstd * g.w + b4.w);
    uint2 pk; pk.x = r0 | (r1 << 16); pk.y = r2 | (r3 << 16);
    *(uint2*)(nh + (size_t)bx * Hd + tid * 4) = pk;
  } else if (bx < BSr + 3072) {
    const int q2 = bx - BSr;
    const float* W = (q2 < 1024) ? Wu : (q2 < 2048) ? Wr : Wo;
    const int i = q2 & 1023;
    float4 v = *(const float4*)(W + (size_t)i * 2048 + tid * 4);
    unsigned r0 = f2bf(v.x), r1 = f2bf(v.y), r2 = f2bf(v.z), r3 = f2bf(v.w);
    uint2 pk; pk.x = r0 | (r1 << 16); pk.y = r2 | (r3 << 16);
    *(uint2*)(Wcat + (size_t)q2 * Hd + tid * 4) = pk;
  } else {
    for (int j = tid; j < Bb * Hd; j += 256) stf[j] = prev_state[j];
    flA[tid] = 0;   // 256 slots = [64][4]
    flB[tid] = 0;
  }
}

// ---------------------------------------------------------------------------
// Kernel 2: xcat = nh @ Wcat^T + bias  (M=16384, N=3072, K=1024, bf16 MFMA)
//   idx = ((t*64 + col/16)*3 + mat)*128 + b*16 + (col&15)   (bf16)
// ---------------------------------------------------------------------------
__global__ __launch_bounds__(256) void k_gemm(
    const unsigned short* __restrict__ nh, const unsigned short* __restrict__ Wcat,
    const float* __restrict__ bu, const float* __restrict__ br,
    const float* __restrict__ bo, unsigned short* __restrict__ xcat)
{
  __shared__ unsigned short aA[8 * 64 * 8];
  __shared__ unsigned short aB[8 * 64 * 8];
  const int tid = threadIdx.x, bx = blockIdx.x;
  const int mt = bx & 127, nt = bx >> 7;
  const int mb = mt * 128, nb = nt * 128;
  const int lane = tid & 63, wave = tid >> 6;
  const int wm = wave >> 1, wn = wave & 1;

  f32x4 acc[4][4];
  f32x4 zz = {0.f, 0.f, 0.f, 0.f};
#pragma unroll
  for (int mi = 0; mi < 4; ++mi)
#pragma unroll
    for (int ni = 0; ni < 4; ++ni) acc[mi][ni] = zz;

  for (int ks = 0; ks < 32; ++ks) {
    const int k0 = ks * 32;
#pragma unroll
    for (int it = 0; it < 4; ++it) {
      int gidx = tid + it * 256;
      int slot = gidx >> 6, l = gidx & 63;
      int kk = k0 + ((l >> 4) << 3);
      int r16 = slot & 7;
      if (slot < 8) {
        int row = mb + r16 * 16 + (l & 15);
        uint4 v = *(const uint4*)(nh + (size_t)row * Hd + kk);
        *(uint4*)(aA + (size_t)(r16 * 64 + l) * 8) = v;
      } else {
        int row = nb + r16 * 16 + (l & 15);
        uint4 v = *(const uint4*)(Wcat + (size_t)row * Hd + kk);
        *(uint4*)(aB + (size_t)(r16 * 64 + l) * 8) = v;
      }
    }
    __syncthreads();
    bf16x8 af_[4], bf_[4];
#pragma unroll
    for (int mi = 0; mi < 4; ++mi)
      af_[mi] = *(const bf16x8*)(aA + ((wm * 4 + mi) * 64 + lane) * 8);
#pragma unroll
    for (int ni = 0; ni < 4; ++ni)
      bf_[ni] = *(const bf16x8*)(aB + ((wn * 4 + ni) * 64 + lane) * 8);
#pragma unroll
    for (int mi = 0; mi < 4; ++mi)
#pragma unroll
      for (int ni = 0; ni < 4; ++ni)
        acc[mi][ni] = __builtin_amdgcn_mfma_f32_16x16x32_bf16(af_[mi], bf_[ni], acc[mi][ni], 0, 0, 0);
    __syncthreads();
  }

#pragma unroll
  for (int ni = 0; ni < 4; ++ni) {
    int n = nb + wn * 64 + ni * 16 + (lane & 15);
    int mat = n >> 10, col = n & 1023;
    float bias = (mat == 0) ? bu[col] : (mat == 1) ? br[col] : bo[col];
#pragma unroll
    for (int mi = 0; mi < 4; ++mi) {
#pragma unroll
      for (int ii = 0; ii < 4; ++ii) {
        int mrow = mb + wm * 64 + mi * 16 + ((lane >> 4) << 2) + ii;
        int b = mrow >> 11, t = mrow & 2047;
        size_t idx = ((size_t)(t * 64 + (col >> 4)) * 3 + mat) * 128 + b * 16 + (col & 15);
        xcat[idx] = (unsigned short)f2bf(acc[mi][ni][ii] + bias);
      }
    }
  }
}

// ---------------------------------------------------------------------------
// Kernel 3: flag-gated dataflow scan. 64 WGs x 256 threads.
// ---------------------------------------------------------------------------
__global__ __launch_bounds__(256, 1) void k_scan(
    const float* __restrict__ Wu, const float* __restrict__ Wr,
    const float* __restrict__ Wo,
    const float* __restrict__ st_g, const float* __restrict__ st_b,
    const float* __restrict__ out_g, const float* __restrict__ out_b,
    const unsigned short* __restrict__ xcat,
    const float* __restrict__ prev_state,
    float* __restrict__ stf, unsigned* __restrict__ rnu,
    unsigned* __restrict__ flA, unsigned* __restrict__ flB,
    float* __restrict__ out)
{
  extern __shared__ char smem[];
  unsigned short* wU = (unsigned short*)smem;          // 32KB
  unsigned short* wR = wU + 2048 * 8;                  // 32KB
  unsigned short* wO = wR + 2048 * 8;                  // 32KB
  char*  afb    = (char*)(wO + 2048 * 8);              // 32KB A-frag buffer
  float* st_own = (float*)(afb + 32768);               // [128]
  float* mv     = st_own + 128;                        // [16]

  const int tid = threadIdx.x;
  const int wg = blockIdx.x;
  const int colbase = wg * COLS;
  const int lane = tid & 63;
  const int wave = tid >> 6;
  const int bmy = tid >> 5;      // batch row (0..7)
  const int imy = tid & 31;      // k-chunk (32 elems)
  const int k0my = imy * 32;

  // ---- one-time init: weight fragments into LDS (B-frag order) ----
  for (int mtx = 0; mtx < 3; ++mtx) {
    const float* W = (mtx == 0) ? Wu : (mtx == 1) ? Wr : Wo;
    unsigned short* dst = (mtx == 0) ? wU : (mtx == 1) ? wR : wO;
    for (int s = tid; s < 2048; s += 256) {
      int ks = s >> 6, l = s & 63;
      int c = l & 15, kg = l >> 4;
      int k0 = ks * 32 + kg * 8;
      const float* src = W + (size_t)(colbase + c) * 2048 + 1024 + k0;
      float4 v0 = *(const float4*)(src);
      float4 v1 = *(const float4*)(src + 4);
      bf16x8 pk;
      pk[0] = (short)f2bf(v0.x); pk[1] = (short)f2bf(v0.y);
      pk[2] = (short)f2bf(v0.z); pk[3] = (short)f2bf(v0.w);
      pk[4] = (short)f2bf(v1.x); pk[5] = (short)f2bf(v1.y);
      pk[6] = (short)f2bf(v1.z); pk[7] = (short)f2bf(v1.w);
      *(bf16x8*)(dst + (size_t)s * 8) = pk;
    }
  }
  // zero A-frag rows 8..15 (padding batch rows) once
  for (int s = tid; s < 2048; s += 256) {
    int l = s & 63, ks = s >> 6;
    if ((l & 15) >= 8)
      *(uint4*)(afb + (((s * 16) ^ ((ks & 7) << 4)))) = make_uint4(0, 0, 0, 0);
  }
  float stg[32], stb[32];
#pragma unroll
  for (int j = 0; j < 32; j += 4) {
    float4 g = *(const float4*)(st_g + k0my + j);
    stg[j] = g.x; stg[j + 1] = g.y; stg[j + 2] = g.z; stg[j + 3] = g.w;
    float4 b4 = *(const float4*)(st_b + k0my + j);
    stb[j] = b4.x; stb[j + 1] = b4.y; stb[j + 2] = b4.z; stb[j + 3] = b4.w;
  }
  // R7 FIX: ALL waves need out_g/out_b at their owned column (waves 2/3 write
  // the sequence output; R6 left these zero there -> zero output).
  float outg_my, outb_my, stgo = 0.f, stbo = 0.f;
  {
    int c = colbase + (tid & 15);
    outg_my = out_g[c]; outb_my = out_b[c];
  }
  if (tid < 128) {
    int c = colbase + (tid & 15);
    st_own[tid] = prev_state[(tid >> 4) * Hd + c];
  }
  if (wave == 1 && lane < 32) {
    int c = colbase + (lane & 15);
    stgo = st_g[c]; stbo = st_b[c];
  }
  __syncthreads();

  float uv[4] = {0.f, 0.f, 0.f, 0.f};

  for (int t = 0; t < Ss; ++t) {
    // prefetch x-projections (independent of state)
    float xu[4] = {0, 0, 0, 0}, xo[4] = {0, 0, 0, 0}, xr[4] = {0, 0, 0, 0};
    if (lane < 32) {
      int b4i = (lane >> 4) * 4, c = lane & 15;
      size_t base = ((size_t)(t * 64 + wg) * 3) * 128;
      if (wave == 0) {
#pragma unroll
        for (int i = 0; i < 4; ++i) {
          xu[i] = bf2f(xcat[base + 0 * 128 + (b4i + i) * 16 + c]);
          xo[i] = bf2f(xcat[base + 2 * 128 + (b4i + i) * 16 + c]);
        }
      } else if (wave == 1) {
#pragma unroll
        for (int i = 0; i < 4; ++i)
          xr[i] = bf2f(xcat[base + 1 * 128 + (b4i + i) * 16 + c]);
      }
    }

    // ---- phase A: flag-wait (wave0 only), then one-shot state read ----
    if (wave == 0) {
      const unsigned tgt = (unsigned)t;
      unsigned fv;
      do {
        fv = __hip_atomic_load(flA + lane * 4, __ATOMIC_RELAXED, SC_SYS);
      } while (__ballot(fv < tgt) != 0ULL);
    }
    __syncthreads();                               // B1

    float sv[32];
    {
      const unsigned long long* sp =
          (const unsigned long long*)(stf + bmy * 1024 + k0my);
#pragma unroll
      for (int j = 0; j < 16; ++j) {
        unsigned long long w = __hip_atomic_load(sp + j, __ATOMIC_RELAXED, SC_SYS);
        sv[2 * j]     = __uint_as_float((unsigned)w);
        sv[2 * j + 1] = __uint_as_float((unsigned)(w >> 32));
      }
    }
    float s = 0.f, q = 0.f;
#pragma unroll
    for (int j = 0; j < 32; ++j) { s += sv[j]; q += sv[j] * sv[j]; }
#pragma unroll
    for (int m = 1; m < 32; m <<= 1) { s += __shfl_xor(s, m); q += __shfl_xor(q, m); }
    if (imy == 0) { mv[bmy * 2] = s; mv[bmy * 2 + 1] = q; }
    __syncthreads();                               // B2: mv ready

    // out[t-1] by waves 2,3 (keeps wave0/1 vmem queues clean)
    if (tid >= 128 && t > 0) {
      int idx = tid - 128, b = idx >> 4, c = idx & 15;
      float sval = st_own[idx];
      float m = mv[b * 2] * (1.0f / Hd);
      float rstd = rsqrtf(mv[b * 2 + 1] * (1.0f / Hd) - m * m + EPSf);
      out[(size_t)b * Ss * Hd + (size_t)(t - 1) * Hd + colbase + c] =
          (sval - m) * rstd * outg_my + outb_my;
    }

    // build ns A-fragments
    {
      float m = mv[bmy * 2] * (1.0f / Hd);
      float rstd = rsqrtf(mv[bmy * 2 + 1] * (1.0f / Hd) - m * m + EPSf);
#pragma unroll
      for (int kg = 0; kg < 4; ++kg) {
        bf16x8 pk;
#pragma unroll
        for (int j = 0; j < 8; ++j) {
          float f = (sv[kg * 8 + j] - m) * rstd * stg[kg * 8 + j] + stb[kg * 8 + j];
          pk[j] = (short)f2bf(f);
        }
        int sidx = imy * 64 + kg * 16 + bmy;
        *(bf16x8*)(afb + ((sidx * 16) ^ ((imy & 7) << 4))) = pk;
      }
    }
    __syncthreads();                               // B3: afb ready

    // MFMA: wave0 -> u; wave1 -> r, publish rn + flagB
    if (wave < 2) {
      const unsigned short* wsel = (wave == 0) ? wU : wR;
      f32x4 acc = {0.f, 0.f, 0.f, 0.f};
#pragma unroll 4
      for (int ks = 0; ks < 32; ++ks) {
        bf16x8 a = *(const bf16x8*)(afb + (((ks * 64 + lane) * 16) ^ ((ks & 7) << 4)));
        bf16x8 w8 = *(const bf16x8*)(wsel + (size_t)(ks * 64 + lane) * 8);
        acc = __builtin_amdgcn_mfma_f32_16x16x32_bf16(a, w8, acc, 0, 0, 0);
      }
      if (wave == 0) {
        if (lane < 32) {
#pragma unroll
          for (int i = 0; i < 4; ++i)
            uv[i] = 1.0f / (1.0f + __expf(-(acc[i] + xu[i])));
        }
      } else {
        if (lane < 32) {
          int c = lane & 15;
#pragma unroll
          for (int i = 0; i < 4; ++i) {
            int b = (lane >> 4) * 4 + i;
            float rvv = 1.0f / (1.0f + __expf(-(acc[i] + xr[i])));
            float m = mv[b * 2] * (1.0f / Hd);
            float rstd = rsqrtf(mv[b * 2 + 1] * (1.0f / Hd) - m * m + EPSf);
            float nso = (st_own[b * 16 + c] - m) * rstd * stgo + stbo;
            __hip_atomic_store(rnu + b * 1024 + colbase + c,
                               f2bf(rvv * nso), __ATOMIC_RELAXED, SC_SYS);
          }
        }
        asm volatile("s_waitcnt vmcnt(0)" ::: "memory");
        if (lane == 0)
          __hip_atomic_store(flB + wg * 4, (unsigned)(t + 1),
                             __ATOMIC_RELAXED, SC_SYS);
      }
    }

    // ---- phase B: flag-wait, then one-shot rn read ----
    if (wave == 0) {
      const unsigned tgt = (unsigned)(t + 1);
      unsigned fv;
      do {
        fv = __hip_atomic_load(flB + lane * 4, __ATOMIC_RELAXED, SC_SYS);
      } while (__ballot(fv < tgt) != 0ULL);
    }
    __syncthreads();                               // B4

    unsigned rw[32];
    {
      const unsigned long long* rp =
          (const unsigned long long*)(rnu + bmy * 1024 + k0my);
#pragma unroll
      for (int j = 0; j < 16; ++j) {
        unsigned long long w = __hip_atomic_load(rp + j, __ATOMIC_RELAXED, SC_SYS);
        rw[2 * j]     = (unsigned)w;
        rw[2 * j + 1] = (unsigned)(w >> 32);
      }
    }
#pragma unroll
    for (int kg = 0; kg < 4; ++kg) {
      bf16x8 pk;
#pragma unroll
      for (int j = 0; j < 8; ++j)
        pk[j] = (short)(unsigned short)(rw[kg * 8 + j] & 0xFFFFu);
      int sidx = imy * 64 + kg * 16 + bmy;
      *(bf16x8*)(afb + ((sidx * 16) ^ ((imy & 7) << 4))) = pk;
    }
    __syncthreads();                               // B5: afb ready

    // candidate MFMA + state update (wave0), publish state + flagA
    if (wave == 0) {
      f32x4 acc = {0.f, 0.f, 0.f, 0.f};
#pragma unroll 4
      for (int ks = 0; ks < 32; ++ks) {
        bf16x8 a = *(const bf16x8*)(afb + (((ks * 64 + lane) * 16) ^ ((ks & 7) << 4)));
        bf16x8 w8 = *(const bf16x8*)(wO + (size_t)(ks * 64 + lane) * 8);
        acc = __builtin_amdgcn_mfma_f32_16x16x32_bf16(a, w8, acc, 0, 0, 0);
      }
      if (lane < 32) {
        int c = lane & 15;
#pragma unroll
        for (int i = 0; i < 4; ++i) {
          int b = (lane >> 4) * 4 + i;
          float cd = tanhf(acc[i] + xo[i]);
          float sold = st_own[b * 16 + c];
          float nsv = (1.0f - uv[i]) * sold + uv[i] * cd;
          st_own[b * 16 + c] = nsv;
          __hip_atomic_store(stf + b * 1024 + colbase + c, nsv,
                             __ATOMIC_RELAXED, SC_SYS);
        }
      }
      asm volatile("s_waitcnt vmcnt(0)" ::: "memory");
      if (lane == 0)
        __hip_atomic_store(flA + wg * 4, (unsigned)(t + 1),
                           __ATOMIC_RELAXED, SC_SYS);
    }
    // no trailing barrier: next step's flag-wait + B1 provide ordering
  }

  // ---- epilogue: out[S-1] + final_state ----
  if (wave == 0) {
    const unsigned tgt = (unsigned)Ss;
    unsigned fv;
    do {
      fv = __hip_atomic_load(flA + lane * 4, __ATOMIC_RELAXED, SC_SYS);
    } while (__ballot(fv < tgt) != 0ULL);
  }
  __syncthreads();
  {
    float s = 0.f, q = 0.f;
    const unsigned long long* sp =
        (const unsigned long long*)(stf + bmy * 1024 + k0my);
#pragma unroll
    for (int j = 0; j < 16; ++j) {
      unsigned long long w = __hip_atomic_load(sp + j, __ATOMIC_RELAXED, SC_SYS);
      float a = __uint_as_float((unsigned)w);
      float b = __uint_as_float((unsigned)(w >> 32));
      s += a + b; q += a * a + b * b;
    }
#pragma unroll
    for (int m = 1; m < 32; m <<= 1) { s += __shfl_xor(s, m); q += __shfl_xor(q, m); }
    if (imy == 0) { mv[bmy * 2] = s; mv[bmy * 2 + 1] = q; }
    __syncthreads();
    if (tid < 128) {
      int b = tid >> 4, c = tid & 15;
      float sval = st_own[tid];
      float m = mv[b * 2] * (1.0f / Hd);
      float rstd = rsqrtf(mv[b * 2 + 1] * (1.0f / Hd) - m * m + EPSf);
      out[(size_t)b * Ss * Hd + (size_t)(Ss - 1) * Hd + colbase + c] =
          (sval - m) * rstd * outg_my + outb_my;
      out[(size_t)Bb * Ss * Hd + b * Hd + colbase + c] = sval;
    }
  }
}

// ---------------------------------------------------------------------------
extern "C" void kernel_launch(void* const* d_in, const int* in_sizes, int n_in,
                              void* d_out, int out_size, void* d_ws, size_t ws_size,
                              hipStream_t stream) {
  const float* hidden = (const float*)d_in[0];
  const float* prev   = (const float*)d_in[1];
  const float* in_g   = (const float*)d_in[2];
  const float* in_b   = (const float*)d_in[3];
  const float* st_g   = (const float*)d_in[4];
  const float* st_b   = (const float*)d_in[5];
  const float* out_g  = (const float*)d_in[6];
  const float* out_b  = (const float*)d_in[7];
  const float* Wu     = (const float*)d_in[8];
  const float* bu     = (const float*)d_in[9];
  const float* Wr     = (const float*)d_in[10];
  const float* br     = (const float*)d_in[11];
  const float* Wo     = (const float*)d_in[12];
  const float* bo     = (const float*)d_in[13];

  char* ws = (char*)d_ws;
  float*          stf  = (float*)(ws + OFF_ST);
  unsigned*       rnu  = (unsigned*)(ws + OFF_RN);
  unsigned*       flA  = (unsigned*)(ws + OFF_FLA);
  unsigned*       flB  = (unsigned*)(ws + OFF_FLB);
  unsigned short* nh   = (unsigned short*)(ws + OFF_NH);
  unsigned short* Wcat = (unsigned short*)(ws + OFF_WCAT);
  unsigned short* xcat = (unsigned short*)(ws + OFF_XCAT);
  float*          out  = (float*)d_out;

  (void)hipFuncSetAttribute(reinterpret_cast<const void*>(k_scan),
                            hipFuncAttributeMaxDynamicSharedMemorySize, SCAN_LDS);

  k_prep<<<dim3(BSr + 3072 + 1), dim3(256), 0, stream>>>(
      hidden, in_g, in_b, prev, Wu, Wr, Wo, nh, Wcat, stf, flA, flB);
  k_gemm<<<dim3(3072), dim3(256), 0, stream>>>(nh, Wcat, bu, br, bo, xcat);
  k_scan<<<dim3(NWG), dim3(256), SCAN_LDS, stream>>>(
      Wu, Wr, Wo, st_g, st_b, out_g, out_b, xcat, prev, stf, rnu, flA, flB, out);
}